// Round 2
// baseline (558.485 us; speedup 1.0000x reference)
//
#include <hip/hip_runtime.h>
#include <hip/hip_bf16.h>
#include <stdint.h>
#include <stddef.h>

// Problem constants (B=4, S=2048, D_IN=D_OUT=4096, r=16, scaling/r = 1.0)
#define D_IN   4096
#define D_OUT  4096
#define M_TOT  8192
#define R_RANK 16
#define LORA_SCALE 1.0f    // SCALING / R = 16/16

typedef __attribute__((ext_vector_type(8))) short short8;    // 8 x bf16 (4 VGPRs)
typedef __attribute__((ext_vector_type(4))) short short4v;   // 4 x bf16 (2 VGPRs)
typedef __attribute__((ext_vector_type(16))) float f32x16;   // 32x32 MFMA acc

// async global->LDS, 16B per lane. LDS dest must be wave-uniform base + lane*16.
#define GL2LDS16(g, l)                                                  \
  __builtin_amdgcn_global_load_lds(                                     \
      (const __attribute__((address_space(1))) void*)(g),               \
      (__attribute__((address_space(3))) void*)(l), 16, 0, 0)

// ---------------------------------------------------------------------------
// pack_prep (fused): blocks [0, PACK_BLOCKS) convert x fp32->bf16 (8/thread);
// blocks [PACK_BLOCKS, PACK_BLOCKS+PREP_BLOCKS) fold LoRA into W and cast.
// Fusing overlaps the two HBM streams and drops one launch.
// ---------------------------------------------------------------------------
#define PACK_BLOCKS 16384  // M_TOT*D_IN/(256*8)
#define PREP_BLOCKS 4096   // (D_IN/1024)*(D_OUT/4)

__global__ __launch_bounds__(256) void pack_prep(
    const float* __restrict__ x, __hip_bfloat16* __restrict__ Xp,
    const float* __restrict__ W, const float* __restrict__ A,
    const float* __restrict__ c, const float* __restrict__ B,
    __hip_bfloat16* __restrict__ Wp) {
  if (blockIdx.x < PACK_BLOCKS) {
    size_t idx = ((size_t)blockIdx.x * 256 + threadIdx.x) * 8;
    float4 v0 = *(const float4*)(x + idx);
    float4 v1 = *(const float4*)(x + idx + 4);
    __hip_bfloat16 t[8];
    t[0] = __float2bfloat16(v0.x); t[1] = __float2bfloat16(v0.y);
    t[2] = __float2bfloat16(v0.z); t[3] = __float2bfloat16(v0.w);
    t[4] = __float2bfloat16(v1.x); t[5] = __float2bfloat16(v1.y);
    t[6] = __float2bfloat16(v1.z); t[7] = __float2bfloat16(v1.w);
    *(short8*)(Xp + idx) = *(const short8*)t;
    return;
  }
  int bid = blockIdx.x - PACK_BLOCKS;
  int t  = threadIdx.x;
  int i  = (bid & 3) * 1024 + t * 4;
  int o0 = (bid >> 2) * 4;

  float4 a4[R_RANK];
#pragma unroll
  for (int r = 0; r < R_RANK; r++) {
    float4 v = *(const float4*)(A + r * D_IN + i);
    float cr = c[r] * LORA_SCALE;
    v.x *= cr; v.y *= cr; v.z *= cr; v.w *= cr;
    a4[r] = v;
  }
#pragma unroll
  for (int oo = 0; oo < 4; oo++) {
    int o = o0 + oo;
    float4 w = *(const float4*)(W + (size_t)o * D_IN + i);
#pragma unroll
    for (int r = 0; r < R_RANK; r++) {
      float br = B[o * R_RANK + r];
      w.x += br * a4[r].x; w.y += br * a4[r].y;
      w.z += br * a4[r].z; w.w += br * a4[r].w;
    }
    __hip_bfloat16 tb[4];
    tb[0] = __float2bfloat16(w.x); tb[1] = __float2bfloat16(w.y);
    tb[2] = __float2bfloat16(w.z); tb[3] = __float2bfloat16(w.w);
    *(short4v*)(Wp + (size_t)o * D_IN + i) = *(const short4v*)tb;
  }
}

// ---------------------------------------------------------------------------
// gemm_256: 256x256 tile, BK=64, 512 threads (8 waves, 2Mx4N), 8-phase
// schedule with counted vmcnt (T3+T4), setprio (T5). THIS ROUND:
//  - mfma_f32_32x32x16_bf16 (per-SIMD 32.3 cyc / 32768 FLOP vs 16x16's
//    19.4 cyc / 16384 FLOP: -17% MFMA pipe time at same data movement)
//  - fragment-ordered LDS: each 1KiB "seg" holds one (32-row-block, 16-K)
//    fragment in lane order, so ds_read_b128 is base + lane*16 + imm ->
//    sequential, zero bank conflicts, near-zero VALU address math.
//    Deposit stays linear (gload_lds constraint); the permutation is
//    applied to the per-lane GLOBAL source address (rule #21).
//
// Fragment layout (analog of proven 16x16x32 row=lane&15,k=(lane>>4)*8):
//   A 32x16 frag: lane l holds A[rb*32 + (l&31)][kf*16 + (l>>5)*8 .. +8]
//   B 32x16 frag: lane l holds B[cb*32 + (l&31)][kf*16 + (l>>5)*8 .. +8]
//   C/D: col = lane&31, row = (reg&3) + 8*(reg>>2) + 4*(lane>>5)  [m74/m101]
//
// LDS: smem[buf][A|B][half][16 segs x 512 bf16] = 128 KiB.
//   seg index s in a half: rb_global = s&7 (8 x 32 rows = 256), kfh = s>>3
//   (kf = half*2 + kfh). Wave-issue w of a stage covers exactly seg w.
//
// Phases per K-tile (4), vmcnt(4) only at ph1/ph3 end (counted, never 0
// in main loop). Accounting identical to the verified round-1 schedule:
// 2 loads/thread/half-stage, <=8 outstanding at each check.
// ---------------------------------------------------------------------------
#define BK 64
#define NT (D_IN / BK)  // 64

#define SOFF(BUFI, AB, KH) ((((BUFI) * 2 + (AB)) * 2 + (KH)) * 8192)

#define VMCNT(N) asm volatile("s_waitcnt vmcnt(" #N ")" ::: "memory")
#define HARD_BARRIER() asm volatile("s_barrier" ::: "memory")
#define SOFT_BARRIER() __builtin_amdgcn_s_barrier()

// stage one half-tile (16 segs x 1KiB = 16KiB) of tile TS into (BUFI,AB,H).
// 2 x global_load_lds(16B) per thread; wave w deposits seg (is*8 + w).
#define STAGE_HALF(BUFI, AB, H, TS)                                          \
  do {                                                                       \
    const __hip_bfloat16* _src = (AB) ? Wp : Xp;                             \
    const int _rb0 = (AB) ? n0 : m0;                                         \
    _Pragma("unroll")                                                        \
    for (int _is = 0; _is < 2; ++_is) {                                      \
      const int _p = _is * 512 + tid;     /* 0..1023 */                      \
      const int _s = _p >> 6;             /* seg 0..15 */                    \
      const int _j = _p & 63;             /* lane slot in seg */             \
      const int _row = (_s & 7) * 32 + (_j & 31);                            \
      const int _k = ((H) * 2 + (_s >> 3)) * 16 + (_j >> 5) * 8;             \
      GL2LDS16(_src + (size_t)(_rb0 + _row) * D_IN + (TS) * BK + _k,         \
               smem + SOFF(BUFI, AB, H) + _p * 8);                           \
    }                                                                        \
  } while (0)

// af[i]: i = kfh*2 + rb_local (rb_local in 0..1 relative to RH*2)
#define LOAD_AF(BUFI, H, RH)                                                 \
  _Pragma("unroll")                                                          \
  for (int _i = 0; _i < 4; ++_i)                                             \
    af[_i] = *(const short8*)(smem + SOFF(BUFI, 0, H) +                      \
                              ((_i >> 1) * 8 + wm * 4 + (RH) * 2 +           \
                               (_i & 1)) * 512 + lane * 8);

// bf[i]: i = kfh*2 + nb
#define LOAD_BF(BUFI, H)                                                     \
  _Pragma("unroll")                                                          \
  for (int _i = 0; _i < 4; ++_i)                                             \
    bf[_i] = *(const short8*)(smem + SOFF(BUFI, 1, H) +                      \
                              ((_i >> 1) * 8 + wn * 2 + (_i & 1)) * 512 +    \
                              lane * 8);

// 8 MFMA: rb pair (RH*2 + r) x nb(0..1) x kfh(0..1); kfh inner-most spacing
// gives 4 independent accs between same-acc reuses.
#define MFMA_QUAD(RH)                                                        \
  do {                                                                       \
    __builtin_amdgcn_s_setprio(1);                                           \
    _Pragma("unroll")                                                        \
    for (int _kfh = 0; _kfh < 2; ++_kfh)                                     \
      _Pragma("unroll")                                                      \
      for (int _r = 0; _r < 2; ++_r)                                         \
        _Pragma("unroll")                                                    \
        for (int _n = 0; _n < 2; ++_n)                                       \
          acc[(RH) * 2 + _r][_n] = __builtin_amdgcn_mfma_f32_32x32x16_bf16(  \
              af[_kfh * 2 + _r], bf[_kfh * 2 + _n],                          \
              acc[(RH) * 2 + _r][_n], 0, 0, 0);                              \
    __builtin_amdgcn_s_setprio(0);                                           \
  } while (0)

// DO_STAGE is a compile-time literal 0/1.
#define TILE_BODY(BUFI, NBUF, T, DO_STAGE)                                   \
  do {                                                                       \
    /* ph0: K-half0, rb{0,1} */                                              \
    LOAD_AF(BUFI, 0, 0);                                                     \
    LOAD_BF(BUFI, 0);                                                        \
    if (DO_STAGE) STAGE_HALF(NBUF, 0, 0, (T) + 1);                           \
    SOFT_BARRIER();                                                          \
    MFMA_QUAD(0);                                                            \
    SOFT_BARRIER();                                                          \
    /* ph1: K-half0, rb{2,3} */                                              \
    LOAD_AF(BUFI, 0, 1);                                                     \
    if (DO_STAGE) STAGE_HALF(NBUF, 1, 0, (T) + 1);                           \
    SOFT_BARRIER();                                                          \
    MFMA_QUAD(1);                                                            \
    if (DO_STAGE) { VMCNT(4); } else { VMCNT(0); }                           \
    HARD_BARRIER();                                                          \
    /* ph2: K-half1, rb{0,1} */                                              \
    LOAD_AF(BUFI, 1, 0);                                                     \
    LOAD_BF(BUFI, 1);                                                        \
    if (DO_STAGE) STAGE_HALF(NBUF, 0, 1, (T) + 1);                           \
    SOFT_BARRIER();                                                          \
    MFMA_QUAD(0);                                                            \
    SOFT_BARRIER();                                                          \
    /* ph3: K-half1, rb{2,3} */                                              \
    LOAD_AF(BUFI, 1, 1);                                                     \
    if (DO_STAGE) STAGE_HALF(NBUF, 1, 1, (T) + 1);                           \
    SOFT_BARRIER();                                                          \
    MFMA_QUAD(1);                                                            \
    if (DO_STAGE) { VMCNT(4); } else { VMCNT(0); }                           \
    HARD_BARRIER();                                                          \
  } while (0)

__global__ __launch_bounds__(512, 2) void gemm_256(
    const __hip_bfloat16* __restrict__ Xp,
    const __hip_bfloat16* __restrict__ Wp,
    const float* __restrict__ bias,
    float* __restrict__ out) {
  // 2 bufs x {A,B} x {kh0,kh1} x 16 segs x 1KiB = 128 KiB (1 block/CU)
  __shared__ __align__(16) __hip_bfloat16 smem[2 * 2 * 2 * 8192];

  const int tid  = threadIdx.x;
  const int wid  = tid >> 6;
  const int lane = tid & 63;
  const int wm = wid >> 2;            // 0..1  (M half: 128 rows)
  const int wn = wid & 3;             // 0..3  (N quarter: 64 cols)
  const int l31 = lane & 31;
  const int lh  = lane >> 5;          // 0..1
  const int m0 = blockIdx.y * 256;
  const int n0 = blockIdx.x * 256;

  f32x16 acc[4][2];
#pragma unroll
  for (int i = 0; i < 4; i++)
#pragma unroll
    for (int j = 0; j < 2; j++)
#pragma unroll
      for (int k = 0; k < 16; k++) acc[i][j][k] = 0.f;

  short8 af[4];
  short8 bf[4];

  // Prologue: stage tile 0 -> buf0, consumption-priority order.
  STAGE_HALF(0, 0, 0, 0);  // A kh0
  STAGE_HALF(0, 1, 0, 0);  // B kh0
  STAGE_HALF(0, 0, 1, 0);  // A kh1
  STAGE_HALF(0, 1, 1, 0);  // B kh1
  VMCNT(4);                // A/B kh0 landed; kh1 still in flight
  HARD_BARRIER();

#pragma unroll 1
  for (int t = 0; t < NT - 2; t += 2) {
    TILE_BODY(0, 1, t, 1);       // compute buf0 (tile t),   stage t+1 -> buf1
    TILE_BODY(1, 0, t + 1, 1);   // compute buf1 (tile t+1), stage t+2 -> buf0
  }
  TILE_BODY(0, 1, NT - 2, 1);    // tile 62, stages tile 63 -> buf1
  TILE_BODY(1, 0, NT - 1, 0);    // tile 63, epilogue (drain with vmcnt(0))

  // Epilogue: 32x32 C/D: col = lane&31, row = (reg&3)+8*(reg>>2)+4*(lane>>5)
  float bv[2];
#pragma unroll
  for (int nb = 0; nb < 2; ++nb) bv[nb] = bias[n0 + wn * 64 + nb * 32 + l31];
#pragma unroll
  for (int rb = 0; rb < 4; ++rb) {
#pragma unroll
    for (int r = 0; r < 16; ++r) {
      const int row = m0 + wm * 128 + rb * 32 + (r & 3) + 8 * (r >> 2) + 4 * lh;
      float* po = out + (size_t)row * D_OUT + n0 + wn * 64 + l31;
      po[0]  = acc[rb][0][r] + bv[0];
      po[32] = acc[rb][1][r] + bv[1];
    }
  }
}

// ---------------------------------------------------------------------------
extern "C" void kernel_launch(void* const* d_in, const int* in_sizes, int n_in,
                              void* d_out, int out_size, void* d_ws, size_t ws_size,
                              hipStream_t stream) {
  const float* x  = (const float*)d_in[0];   // [4,2048,4096]
  const float* W  = (const float*)d_in[1];   // [4096,4096]
  const float* b  = (const float*)d_in[2];   // [4096]
  const float* lA = (const float*)d_in[3];   // [16,4096]
  const float* lB = (const float*)d_in[4];   // [4096,16]
  const float* lc = (const float*)d_in[5];   // [16,1]
  float* out = (float*)d_out;                // [4,2048,4096] fp32

  char* ws = (char*)d_ws;
  __hip_bfloat16* Xp = (__hip_bfloat16*)ws;                       // 64 MiB
  __hip_bfloat16* Wp = (__hip_bfloat16*)(ws + (size_t)67108864);  // 32 MiB

  pack_prep<<<dim3(PACK_BLOCKS + PREP_BLOCKS), dim3(256), 0, stream>>>(
      x, Xp, W, lA, lc, lB, Wp);
  gemm_256<<<dim3(D_OUT / 256, M_TOT / 256), dim3(512), 0, stream>>>(Xp, Wp, b, out);
}

// Round 3
// 524.178 us; speedup vs baseline: 1.0654x; 1.0654x over previous
//
#include <hip/hip_runtime.h>
#include <hip/hip_bf16.h>
#include <stdint.h>
#include <stddef.h>

// Problem constants (B=4, S=2048, D_IN=D_OUT=4096, r=16, scaling/r = 1.0)
#define D_IN   4096
#define D_OUT  4096
#define M_TOT  8192
#define R_RANK 16
#define LORA_SCALE 1.0f    // SCALING / R = 16/16

typedef __attribute__((ext_vector_type(8))) short short8;    // 8 x bf16 (4 VGPRs)
typedef __attribute__((ext_vector_type(4))) short short4v;   // 4 x bf16 (2 VGPRs)
typedef __attribute__((ext_vector_type(16))) float f32x16;   // 32x32 MFMA acc

// async global->LDS, 16B per lane. LDS dest must be wave-uniform base + lane*16.
#define GL2LDS16(g, l)                                                  \
  __builtin_amdgcn_global_load_lds(                                     \
      (const __attribute__((address_space(1))) void*)(g),               \
      (__attribute__((address_space(3))) void*)(l), 16, 0, 0)

// ---------------------------------------------------------------------------
// pack_prep (fused): blocks [0, PACK_BLOCKS) convert x fp32->bf16 (8/thread);
// blocks [PACK_BLOCKS, ...) fold LoRA into W and cast. (round-2 version, kept)
// ---------------------------------------------------------------------------
#define PACK_BLOCKS 16384  // M_TOT*D_IN/(256*8)
#define PREP_BLOCKS 4096   // (D_IN/1024)*(D_OUT/4)

__global__ __launch_bounds__(256) void pack_prep(
    const float* __restrict__ x, __hip_bfloat16* __restrict__ Xp,
    const float* __restrict__ W, const float* __restrict__ A,
    const float* __restrict__ c, const float* __restrict__ B,
    __hip_bfloat16* __restrict__ Wp) {
  if (blockIdx.x < PACK_BLOCKS) {
    size_t idx = ((size_t)blockIdx.x * 256 + threadIdx.x) * 8;
    float4 v0 = *(const float4*)(x + idx);
    float4 v1 = *(const float4*)(x + idx + 4);
    __hip_bfloat16 t[8];
    t[0] = __float2bfloat16(v0.x); t[1] = __float2bfloat16(v0.y);
    t[2] = __float2bfloat16(v0.z); t[3] = __float2bfloat16(v0.w);
    t[4] = __float2bfloat16(v1.x); t[5] = __float2bfloat16(v1.y);
    t[6] = __float2bfloat16(v1.z); t[7] = __float2bfloat16(v1.w);
    *(short8*)(Xp + idx) = *(const short8*)t;
    return;
  }
  int bid = blockIdx.x - PACK_BLOCKS;
  int t  = threadIdx.x;
  int i  = (bid & 3) * 1024 + t * 4;
  int o0 = (bid >> 2) * 4;

  float4 a4[R_RANK];
#pragma unroll
  for (int r = 0; r < R_RANK; r++) {
    float4 v = *(const float4*)(A + r * D_IN + i);
    float cr = c[r] * LORA_SCALE;
    v.x *= cr; v.y *= cr; v.z *= cr; v.w *= cr;
    a4[r] = v;
  }
#pragma unroll
  for (int oo = 0; oo < 4; oo++) {
    int o = o0 + oo;
    float4 w = *(const float4*)(W + (size_t)o * D_IN + i);
#pragma unroll
    for (int r = 0; r < R_RANK; r++) {
      float br = B[o * R_RANK + r];
      w.x += br * a4[r].x; w.y += br * a4[r].y;
      w.z += br * a4[r].z; w.w += br * a4[r].w;
    }
    __hip_bfloat16 tb[4];
    tb[0] = __float2bfloat16(w.x); tb[1] = __float2bfloat16(w.y);
    tb[2] = __float2bfloat16(w.z); tb[3] = __float2bfloat16(w.w);
    *(short4v*)(Wp + (size_t)o * D_IN + i) = *(const short4v*)tb;
  }
}

// ---------------------------------------------------------------------------
// gemm_256: 256x256 tile, BK=64, 512 threads (8 waves, 2Mx4N), 8-phase
// schedule with counted vmcnt (T3+T4), setprio (T5).
//
// THIS ROUND: 32x32x16 MFMA (fragment mapping verified in round 2) on the
// ROUND-1 PROVEN LDS layout/staging (round 2's fragment-ordered LDS
// scattered the gload_lds global source 16B-per-row -> 4x VMEM requests;
// reverted). LDS: smem[buf][A|B][kh][256 rows][32 cols] bf16, each K-half a
// contiguous 16KiB block. Staging: 4 lanes cover 64B contiguous per row;
// chunk swizzle phys = log ^ ((row>>1)&3) applied to the GLOBAL source col
// (rule #21: both-sides-or-neither).
//
// 32x32 fragment read: lane l needs row = 32*rb + (l&31), chunk_log =
// kfh*2 + (l>>5). Block bases are multiples of 32 rows so the swizzle term
// (row>>1)&3 == (l31>>1)&3 (per-lane constant). 64 lanes spread exactly
// 8 x 4B accesses per bank per ds_read_b128 = conflict-free optimum.
//
// Phases per K-tile (4), vmcnt(4) only at ph1/ph3 end (counted, never 0
// in main loop) — accounting identical to the verified round-1 schedule.
// ---------------------------------------------------------------------------
#define BK 64
#define NT (D_IN / BK)  // 64

#define SOFF(BUFI, AB, KH) ((((BUFI) * 2 + (AB)) * 2 + (KH)) * 8192)

#define VMCNT(N) asm volatile("s_waitcnt vmcnt(" #N ")" ::: "memory")
#define HARD_BARRIER() asm volatile("s_barrier" ::: "memory")
#define SOFT_BARRIER() __builtin_amdgcn_s_barrier()

// stage one half-tile (256 rows x 32 cols bf16 = 16KiB) of tile TS into
// smem block (BUFI, AB, KH). 2 x global_load_lds(16B) per thread.
// (verbatim round-1 staging: 4 lanes x 64B contiguous per row)
#define STAGE_HALF(BUFI, AB, KH, TS)                                         \
  do {                                                                       \
    const __hip_bfloat16* _src = (AB) ? Wp : Xp;                             \
    const int _rb = (AB) ? n0 : m0;                                          \
    const int _kb = (TS) * BK + (KH) * 32;                                   \
    _Pragma("unroll")                                                        \
    for (int _is = 0; _is < 2; ++_is) {                                      \
      const int _p = _is * 512 + tid;   /* chunk 0..1023 */                  \
      const int _row = _p >> 2;                                              \
      const int _c = (_p & 3) ^ ((_row >> 1) & 3); /* inverse swizzle */     \
      GL2LDS16(_src + (size_t)(_rb + _row) * D_IN + _kb + _c * 8,            \
               smem + SOFF(BUFI, AB, KH) + _p * 8);                          \
    }                                                                        \
  } while (0)

// af[i]: i = kfh*2 + r (r = local 32-row block within the RH pair)
// addr: row = wm*128 + (RH*2+r)*32 + l31, chunk_phys = (kfh*2+lh)^xr
#define LOAD_AF(BUFI, H, RH)                                                 \
  _Pragma("unroll")                                                          \
  for (int _i = 0; _i < 4; ++_i)                                             \
    af[_i] = *(const short8*)(smem + SOFF(BUFI, 0, H) +                      \
                              (wm * 128 + ((RH) * 2 + (_i & 1)) * 32 + l31)  \
                                  * 32 +                                     \
                              (((_i >> 1) * 2 + lh) ^ xr) * 8);

// bf[i]: i = kfh*2 + nb ; row = wn*64 + nb*32 + l31
#define LOAD_BF(BUFI, H)                                                     \
  _Pragma("unroll")                                                          \
  for (int _i = 0; _i < 4; ++_i)                                             \
    bf[_i] = *(const short8*)(smem + SOFF(BUFI, 1, H) +                      \
                              (wn * 64 + (_i & 1) * 32 + l31) * 32 +         \
                              (((_i >> 1) * 2 + lh) ^ xr) * 8);

// 8 MFMA: (rb = RH*2 + r) x nb x kfh; kfh outer -> 4 independent accs
// between same-acc reuses.
#define MFMA_QUAD(RH)                                                        \
  do {                                                                       \
    __builtin_amdgcn_s_setprio(1);                                           \
    _Pragma("unroll")                                                        \
    for (int _kfh = 0; _kfh < 2; ++_kfh)                                     \
      _Pragma("unroll")                                                      \
      for (int _r = 0; _r < 2; ++_r)                                         \
        _Pragma("unroll")                                                    \
        for (int _n = 0; _n < 2; ++_n)                                       \
          acc[(RH) * 2 + _r][_n] = __builtin_amdgcn_mfma_f32_32x32x16_bf16(  \
              af[_kfh * 2 + _r], bf[_kfh * 2 + _n],                          \
              acc[(RH) * 2 + _r][_n], 0, 0, 0);                              \
    __builtin_amdgcn_s_setprio(0);                                           \
  } while (0)

// DO_STAGE is a compile-time literal 0/1.
#define TILE_BODY(BUFI, NBUF, T, DO_STAGE)                                   \
  do {                                                                       \
    /* ph0: K-half0, rb{0,1} */                                              \
    LOAD_AF(BUFI, 0, 0);                                                     \
    LOAD_BF(BUFI, 0);                                                        \
    if (DO_STAGE) STAGE_HALF(NBUF, 0, 0, (T) + 1);                           \
    SOFT_BARRIER();                                                          \
    MFMA_QUAD(0);                                                            \
    SOFT_BARRIER();                                                          \
    /* ph1: K-half0, rb{2,3} */                                              \
    LOAD_AF(BUFI, 0, 1);                                                     \
    if (DO_STAGE) STAGE_HALF(NBUF, 1, 0, (T) + 1);                           \
    SOFT_BARRIER();                                                          \
    MFMA_QUAD(1);                                                            \
    if (DO_STAGE) { VMCNT(4); } else { VMCNT(0); }                           \
    HARD_BARRIER();                                                          \
    /* ph2: K-half1, rb{0,1} */                                              \
    LOAD_AF(BUFI, 1, 0);                                                     \
    LOAD_BF(BUFI, 1);                                                        \
    if (DO_STAGE) STAGE_HALF(NBUF, 0, 1, (T) + 1);                           \
    SOFT_BARRIER();                                                          \
    MFMA_QUAD(0);                                                            \
    SOFT_BARRIER();                                                          \
    /* ph3: K-half1, rb{2,3} */                                              \
    LOAD_AF(BUFI, 1, 1);                                                     \
    if (DO_STAGE) STAGE_HALF(NBUF, 1, 1, (T) + 1);                           \
    SOFT_BARRIER();                                                          \
    MFMA_QUAD(1);                                                            \
    if (DO_STAGE) { VMCNT(4); } else { VMCNT(0); }                           \
    HARD_BARRIER();                                                          \
  } while (0)

__global__ __launch_bounds__(512, 2) void gemm_256(
    const __hip_bfloat16* __restrict__ Xp,
    const __hip_bfloat16* __restrict__ Wp,
    const float* __restrict__ bias,
    float* __restrict__ out) {
  // 2 bufs x {A,B} x {kh0,kh1} x 256x32 bf16 = 128 KiB (1 block/CU)
  __shared__ __align__(16) __hip_bfloat16 smem[2 * 2 * 2 * 8192];

  const int tid  = threadIdx.x;
  const int wid  = tid >> 6;
  const int lane = tid & 63;
  const int wm = wid >> 2;            // 0..1  (M half: 128 rows)
  const int wn = wid & 3;             // 0..3  (N quarter: 64 cols)
  const int l31 = lane & 31;
  const int lh  = lane >> 5;          // 0..1
  const int xr  = (l31 >> 1) & 3;     // swizzle term (block bases %32 == 0)
  const int m0 = blockIdx.y * 256;
  const int n0 = blockIdx.x * 256;

  f32x16 acc[4][2];
#pragma unroll
  for (int i = 0; i < 4; i++)
#pragma unroll
    for (int j = 0; j < 2; j++)
#pragma unroll
      for (int k = 0; k < 16; k++) acc[i][j][k] = 0.f;

  short8 af[4];
  short8 bf[4];

  // Prologue: stage tile 0 -> buf0, consumption-priority order.
  STAGE_HALF(0, 0, 0, 0);  // A kh0
  STAGE_HALF(0, 1, 0, 0);  // B kh0
  STAGE_HALF(0, 0, 1, 0);  // A kh1
  STAGE_HALF(0, 1, 1, 0);  // B kh1
  VMCNT(4);                // A/B kh0 landed; kh1 still in flight
  HARD_BARRIER();

#pragma unroll 1
  for (int t = 0; t < NT - 2; t += 2) {
    TILE_BODY(0, 1, t, 1);       // compute buf0 (tile t),   stage t+1 -> buf1
    TILE_BODY(1, 0, t + 1, 1);   // compute buf1 (tile t+1), stage t+2 -> buf0
  }
  TILE_BODY(0, 1, NT - 2, 1);    // tile 62, stages tile 63 -> buf1
  TILE_BODY(1, 0, NT - 1, 0);    // tile 63, epilogue (drain with vmcnt(0))

  // Epilogue: 32x32 C/D: col = lane&31, row = (reg&3)+8*(reg>>2)+4*(lane>>5)
  float bv[2];
#pragma unroll
  for (int nb = 0; nb < 2; ++nb) bv[nb] = bias[n0 + wn * 64 + nb * 32 + l31];
#pragma unroll
  for (int rb = 0; rb < 4; ++rb) {
#pragma unroll
    for (int r = 0; r < 16; ++r) {
      const int row = m0 + wm * 128 + rb * 32 + (r & 3) + 8 * (r >> 2) + 4 * lh;
      float* po = out + (size_t)row * D_OUT + n0 + wn * 64 + l31;
      po[0]  = acc[rb][0][r] + bv[0];
      po[32] = acc[rb][1][r] + bv[1];
    }
  }
}

// ---------------------------------------------------------------------------
extern "C" void kernel_launch(void* const* d_in, const int* in_sizes, int n_in,
                              void* d_out, int out_size, void* d_ws, size_t ws_size,
                              hipStream_t stream) {
  const float* x  = (const float*)d_in[0];   // [4,2048,4096]
  const float* W  = (const float*)d_in[1];   // [4096,4096]
  const float* b  = (const float*)d_in[2];   // [4096]
  const float* lA = (const float*)d_in[3];   // [16,4096]
  const float* lB = (const float*)d_in[4];   // [4096,16]
  const float* lc = (const float*)d_in[5];   // [16,1]
  float* out = (float*)d_out;                // [4,2048,4096] fp32

  char* ws = (char*)d_ws;
  __hip_bfloat16* Xp = (__hip_bfloat16*)ws;                       // 64 MiB
  __hip_bfloat16* Wp = (__hip_bfloat16*)(ws + (size_t)67108864);  // 32 MiB

  pack_prep<<<dim3(PACK_BLOCKS + PREP_BLOCKS), dim3(256), 0, stream>>>(
      x, Xp, W, lA, lc, lB, Wp);
  gemm_256<<<dim3(D_OUT / 256, M_TOT / 256), dim3(512), 0, stream>>>(Xp, Wp, b, out);
}